// Round 24
// baseline (127.166 us; speedup 1.0000x reference)
//
#include <hip/hip_runtime.h>

typedef __bf16 bf16_t;
typedef __bf16 bf16x8 __attribute__((ext_vector_type(8)));
typedef float  f32x4  __attribute__((ext_vector_type(4)));

#define MFMA16(a, b, c) __builtin_amdgcn_mfma_f32_16x16x32_bf16((a), (b), (c), 0, 0, 0)

__device__ __forceinline__ void gload_lds16(const void* g, void* l) {
  __builtin_amdgcn_global_load_lds((__attribute__((address_space(1))) void*)(g),
                                   (__attribute__((address_space(3))) void*)(l),
                                   16, 0, 0);
}

// ---------------------------------------------------------------- fused convert (x, wq, wk, wv, wo)
__global__ __launch_bounds__(256) void cvt_all(const float* __restrict__ x,
                                               const float* __restrict__ wq,
                                               const float* __restrict__ wk,
                                               const float* __restrict__ wv,
                                               const float* __restrict__ wo,
                                               bf16_t* __restrict__ xb,
                                               bf16_t* __restrict__ wqkv,
                                               bf16_t* __restrict__ wob) {
  int i = (blockIdx.x * 256 + threadIdx.x) * 8;
  const float* src;
  bf16_t* dst;
  int off;
  if (i < 4194304)      { src = x;  dst = xb;             off = i; }
  else if (i < 5242880) { src = wq; dst = wqkv;           off = i - 4194304; }
  else if (i < 5505024) { src = wk; dst = wqkv + 1048576; off = i - 5242880; }
  else if (i < 5767168) { src = wv; dst = wqkv + 1310720; off = i - 5505024; }
  else                  { src = wo; dst = wob;            off = i - 5767168; }
  const float4* pp = reinterpret_cast<const float4*>(src + off);
  float4 a = pp[0], b = pp[1];
  bf16x8 v;
  v[0] = (bf16_t)a.x; v[1] = (bf16_t)a.y; v[2] = (bf16_t)a.z; v[3] = (bf16_t)a.w;
  v[4] = (bf16_t)b.x; v[5] = (bf16_t)b.y; v[6] = (bf16_t)b.z; v[7] = (bf16_t)b.w;
  *reinterpret_cast<bf16x8*>(dst + off) = v;
}

// ---------------------------------------------------------------- GEMM  C[M,N] = A[M,K] * B[N,K]^T
// Template <T, BM, BN>: A-tile BM x 64, B-tile BN x 64; waves 2x2, each wave
// covers (BM/2) x (BN/2). 64x64 tiles -> 16KB LDS, ~64 VGPR -> 4 blocks/CU
// (max TLP for the latency-bound staging loop; exact-packing lever proven
// 3/3 on GEMMs in R22/R23). gemm1 grid (24,64)=1536 = 6 uniform blocks/CU at
// 4-deep concurrency; gemm2 grid (16,64)=1024 = 4/CU exact.
// Dual-write epilogue when kp/vt non-null: cols [1024,1280) -> kp[4][4096][64]
// PRE-SCALED by 0.125*log2(e) (attn uses exp2 directly); cols [1280,1536) ->
// vt[256][4096] transposed (per-element colb logic, BN-independent).
template <typename T, int BM, int BN>
__global__ __launch_bounds__(256) void gemm_bt(const bf16_t* __restrict__ A,
                                               const bf16_t* __restrict__ B,
                                               T* __restrict__ C,
                                               int M, int N, int K,
                                               bf16_t* __restrict__ kp,
                                               bf16_t* __restrict__ vt) {
  constexpr int BK = 64;
  constexpr int MI = BM / 32;                    // row fragments per wave
  constexpr int NJ = BN / 32;                    // col fragments per wave
  int tid  = threadIdx.x;
  int lane = tid & 63, w = tid >> 6;
  int wr = w >> 1, wc = w & 1;
  int l15 = lane & 15, lhi = lane >> 4;
  int row0 = blockIdx.y * BM, col0 = blockIdx.x * BN;

  __shared__ alignas(16) char smem[(BM + BN) * 128];
  char* sA = smem;
  char* sB = smem + BM * 128;

  f32x4 acc[MI][NJ] = {};

  for (int k0 = 0; k0 < K; k0 += BK) {
#pragma unroll
    for (int i = 0; i < BM / 32; ++i) {          // A: BM*8 16B-chunks
      int c = i * 256 + tid;
      int r = c >> 3, kc = c & 7;
      int kk = k0 + ((kc ^ (r & 7)) << 3);
      gload_lds16(A + (size_t)(row0 + r) * K + kk, sA + c * 16);
    }
#pragma unroll
    for (int i = 0; i < BN / 32; ++i) {          // B: BN*8 16B-chunks
      int c = i * 256 + tid;
      int r = c >> 3, kc = c & 7;
      int kk = k0 + ((kc ^ (r & 7)) << 3);
      gload_lds16(B + (size_t)(col0 + r) * K + kk, sB + c * 16);
    }
    __syncthreads();
#pragma unroll
    for (int s = 0; s < 2; ++s) {
      bf16x8 af[MI], bfr[NJ];
#pragma unroll
      for (int mi = 0; mi < MI; ++mi) {
        int r = wr * (BM / 2) + mi * 16 + l15;
        af[mi] = *reinterpret_cast<const bf16x8*>(
            sA + r * 128 + (((s * 4 + lhi) ^ (r & 7)) << 4));
      }
#pragma unroll
      for (int nj = 0; nj < NJ; ++nj) {
        int r = wc * (BN / 2) + nj * 16 + l15;
        bfr[nj] = *reinterpret_cast<const bf16x8*>(
            sB + r * 128 + (((s * 4 + lhi) ^ (r & 7)) << 4));
      }
#pragma unroll
      for (int mi = 0; mi < MI; ++mi)
#pragma unroll
        for (int nj = 0; nj < NJ; ++nj)
          acc[mi][nj] = MFMA16(af[mi], bfr[nj], acc[mi][nj]);
    }
    __syncthreads();
  }

  const float KSCALE = 0.18033688f;   // 0.125 * log2(e)
#pragma unroll
  for (int mi = 0; mi < MI; ++mi)
#pragma unroll
    for (int nj = 0; nj < NJ; ++nj) {
      int colb = col0 + wc * (BN / 2) + nj * 16 + l15;
      int rowb = row0 + wr * (BM / 2) + mi * 16 + lhi * 4;
      if (kp != nullptr && colb >= 1024) {
        if (colb < 1280) {
          int gg = (colb - 1024) >> 6, d = (colb - 1024) & 63;
          bf16_t* kdst = kp + ((size_t)gg * 4096 + rowb) * 64 + d;
#pragma unroll
          for (int r2 = 0; r2 < 4; ++r2)
            kdst[r2 * 64] = (bf16_t)(acc[mi][nj][r2] * KSCALE);
        } else {
          union { bf16_t hh[4]; uint64_t u; } a;
#pragma unroll
          for (int r2 = 0; r2 < 4; ++r2) a.hh[r2] = (bf16_t)acc[mi][nj][r2];
          *reinterpret_cast<uint64_t*>(vt + (size_t)(colb - 1280) * 4096 + rowb) = a.u;
        }
      } else {
#pragma unroll
        for (int r2 = 0; r2 < 4; ++r2)
          C[(size_t)(rowb + r2) * N + colb] = (T)acc[mi][nj][r2];
      }
    }
}

// ---------------------------------------------------------------- flash attention (causal GQA)
// R21 config (best measured: attn 74.4us): BK=64, 4 waves x 16 q-rows, shared
// double-buffered K+V staging via global_load_lds (pre-swizzled source), P via
// wave-private XOR-swizzled LDS, pair-and-split balance (1024 uniform blocks),
// partials straight to scratch, norm_combine. l accumulated on the matrix
// pipe: lacc = mfma(ap, ones, lacc); lacc[r] lane-aligned with O rows.
// K pre-scaled by 0.125*log2(e) -> P = exp2(st) directly.
__global__ __launch_bounds__(256, 2) void attn_kernel(const bf16_t* __restrict__ qkv,
                                                      const bf16_t* __restrict__ kp,
                                                      const bf16_t* __restrict__ vt,
                                                      bf16_t* __restrict__ ctx,
                                                      float* __restrict__ Opart,
                                                      float* __restrict__ lpart) {
  int tid = threadIdx.x, lane = tid & 63, w = tid >> 6;
  int l15 = lane & 15, lhi = lane >> 4;
  int e = l15 & 7;
  int bid = blockIdx.x;
  int pos = bid & 15, qq = bid >> 4;             // qq 0..63
  int p = qq >> 1, half = qq & 1;
  int g = (pos & 7) >> 1;                        // KV group -> XCDs {2g, 2g+1}
  int h = g * 4 + (((pos >> 3) << 1) | (pos & 1));

  __shared__ alignas(16) char kv[2][16384];      // [buf][K 8KB | V 8KB], swizzled
  __shared__ alignas(16) char pb_all[4][2048];   // per-wave P [16 rows][128B], XOR chunks
  char* pbuf = pb_all[w];

  const bf16_t* kbase = kp + (size_t)g * 4096 * 64;
  const bf16_t* vbase = vt + (size_t)g * 64 * 4096;

  auto STAGE = [&](int j0, int b) {
#pragma unroll
    for (int i = 0; i < 2; ++i) {
      int c = i * 256 + tid;                     // 512 chunks of 16B
      int r = c >> 3, kc = c & 7;
      int d8 = kc ^ (r & 7);
      gload_lds16(kbase + (size_t)(j0 + r) * 64 + d8 * 8, &kv[b][c * 16]);
    }
#pragma unroll
    for (int i = 0; i < 2; ++i) {
      int c = i * 256 + tid;
      int r = c >> 3, kc = c & 7;
      int d8 = kc ^ (r & 7);
      gload_lds16(vbase + (size_t)r * 4096 + j0 + d8 * 8, &kv[b][8192 + c * 16]);
    }
  };

  bf16x8 ones;
#pragma unroll
  for (int ii = 0; ii < 8; ++ii) ones[ii] = (bf16_t)1.0f;

  auto runPhase = [&](int tile, int sbeg, int send, bool fin,
                      float* Oslot, float* lslot) {
    int r0 = tile * 64;
    int wr0 = r0 + w * 16;                       // this wave's 16 q-rows

    bf16x8 qf[2];
#pragma unroll
    for (int ks = 0; ks < 2; ++ks)
      qf[ks] = *reinterpret_cast<const bf16x8*>(
          qkv + (size_t)(wr0 + l15) * 1536 + h * 64 + ks * 32 + lhi * 8);

    f32x4 O[4] = {};
    f32x4 lacc = {0.f, 0.f, 0.f, 0.f};

    STAGE(sbeg * 64, 0);
    __syncthreads();

    for (int step = sbeg; step < send; ++step) {
      int b = (step - sbeg) & 1;
      if (step + 1 < send) STAGE((step + 1) * 64, b ^ 1);
      int j0 = step * 64;
      const char* kt  = kv[b];
      const char* vtl = kv[b] + 8192;
      bool diag = (j0 + 64 > r0);
#pragma unroll
      for (int nj = 0; nj < 4; ++nj) {
        int kr = nj * 16 + l15;                  // key row in tile
        const char* krow = kt + kr * 128;
        bf16x8 k0 = *reinterpret_cast<const bf16x8*>(krow + ((lhi ^ (kr & 7)) << 4));
        bf16x8 k1 = *reinterpret_cast<const bf16x8*>(krow + (((4 + lhi) ^ (kr & 7)) << 4));
        f32x4 t = {0.f, 0.f, 0.f, 0.f};
        t = MFMA16(k0, qf[0], t);
        t = MFMA16(k1, qf[1], t);
        if (diag) {
          int qr = wr0 + l15;
#pragma unroll
          for (int r = 0; r < 4; ++r) {
            int key = j0 + nj * 16 + lhi * 4 + r;
            if (key > qr) t[r] = -1e30f;
          }
        }
        int sw = (nj * 2 + (lhi >> 1)) ^ e;      // XOR chunk swizzle (wave-private)
        union { bf16_t hh[4]; uint64_t u; } a;
#pragma unroll
        for (int r = 0; r < 4; ++r) a.hh[r] = (bf16_t)exp2f(t[r]);
        *reinterpret_cast<uint64_t*>(pbuf + l15 * 128 + sw * 16 + ((lhi & 1) << 3)) = a.u;
      }
      // ---- PV: A = P (row = l15), B = V^T (hd = l15); l += P . ones (MFMA)
      bf16x8 ap[2];
#pragma unroll
      for (int ks = 0; ks < 2; ++ks)
        ap[ks] = *reinterpret_cast<const bf16x8*>(
            pbuf + l15 * 128 + (((ks * 4 + lhi) ^ e) << 4));
      lacc = MFMA16(ap[0], ones, lacc);
      lacc = MFMA16(ap[1], ones, lacc);
#pragma unroll
      for (int h4 = 0; h4 < 4; ++h4) {
        int vr = h4 * 16 + l15;                  // hd row in tile
        const char* vrow = vtl + vr * 128;
        bf16x8 v0 = *reinterpret_cast<const bf16x8*>(vrow + ((lhi ^ (vr & 7)) << 4));
        bf16x8 v1 = *reinterpret_cast<const bf16x8*>(vrow + (((4 + lhi) ^ (vr & 7)) << 4));
        O[h4] = MFMA16(ap[0], v0, O[h4]);
        O[h4] = MFMA16(ap[1], v1, O[h4]);
      }
      __syncthreads();   // drains staging vmcnt; protects both buffers
    }

    // ---- epilogue: lacc[r] = l for row wr0+lhi*4+r (lane-aligned with O)
    if (fin) {
#pragma unroll
      for (int h4 = 0; h4 < 4; ++h4)
#pragma unroll
        for (int r = 0; r < 4; ++r) {
          int row = wr0 + lhi * 4 + r;
          ctx[(size_t)row * 1024 + h * 64 + h4 * 16 + l15] =
              (bf16_t)(O[h4][r] / lacc[r]);
        }
    } else {
      if (l15 == 0) {
#pragma unroll
        for (int r = 0; r < 4; ++r) lslot[w * 16 + lhi * 4 + r] = lacc[r];
      }
#pragma unroll
      for (int h4 = 0; h4 < 4; ++h4)
#pragma unroll
        for (int r = 0; r < 4; ++r)
          Oslot[(size_t)(w * 16 + lhi * 4 + r) * 64 + h4 * 16 + l15] = O[h4][r];
    }
  };

  if (half == 0) {
    bool fin = (p == 31);   // tile 32 has exactly 33 steps -> complete
    if (fin) {
      runPhase(63 - p, 0, 33, true, nullptr, nullptr);
    } else {
      int u = (30 - p) * 16 + h;
      runPhase(63 - p, 0, 33, false,
               Opart + ((size_t)u * 2 + 0) * 4096, lpart + ((size_t)u * 2 + 0) * 64);
    }
  } else {
    if (p < 31) {
      int u = (30 - p) * 16 + h;
      runPhase(63 - p, 33, 64 - p, false,
               Opart + ((size_t)u * 2 + 1) * 4096, lpart + ((size_t)u * 2 + 1) * 64);
    }
    runPhase(p, 0, p + 1, true, nullptr, nullptr);
  }
}

// ---------------------------------------------------------------- combine split-tile partials
__global__ __launch_bounds__(256) void norm_combine(const float* __restrict__ Opart,
                                                    const float* __restrict__ lpart,
                                                    bf16_t* __restrict__ ctx) {
  int u = blockIdx.x;
  int T = 33 + (u >> 4), h = u & 15;
  int t = threadIdx.x;
  int row = t >> 2, q = t & 3;                   // 64 rows x 4 quarters
  const float* O0 = Opart + (size_t)u * 2 * 4096;
  const float* O1 = O0 + 4096;
  const float* l0 = lpart + (size_t)u * 2 * 64;
  const float* l1 = l0 + 64;
  float il = 1.0f / (l0[row] + l1[row]);
#pragma unroll
  for (int i = 0; i < 4; ++i) {
    int idx = row * 64 + q * 16 + i * 4;
    f32x4 a = *reinterpret_cast<const f32x4*>(O0 + idx);
    f32x4 b = *reinterpret_cast<const f32x4*>(O1 + idx);
    union { bf16_t hh[4]; uint64_t uu; } o;
#pragma unroll
    for (int r = 0; r < 4; ++r) o.hh[r] = (bf16_t)((a[r] + b[r]) * il);
    *reinterpret_cast<uint64_t*>(
        ctx + (size_t)(T * 64 + row) * 1024 + h * 64 + q * 16 + i * 4) = o.uu;
  }
}

// ---------------------------------------------------------------- launch
extern "C" void kernel_launch(void* const* d_in, const int* in_sizes, int n_in,
                              void* d_out, int out_size, void* d_ws, size_t ws_size,
                              hipStream_t stream) {
  const float* x  = (const float*)d_in[0];
  const float* wq = (const float*)d_in[1];
  const float* wk = (const float*)d_in[2];
  const float* wv = (const float*)d_in[3];
  const float* wo = (const float*)d_in[4];
  float* out = (float*)d_out;

  char* ws = (char*)d_ws;
  size_t off = 0;
  auto alloc = [&](size_t b) {
    char* p = ws + off;
    off += (b + 255) & ~(size_t)255;
    return p;
  };
  // live-through-attn buffers first
  bf16_t* wob  = (bf16_t*)alloc((size_t)1024 * 1024 * 2);
  bf16_t* qkv  = (bf16_t*)alloc((size_t)4096 * 1536 * 2);
  bf16_t* vtb  = (bf16_t*)alloc((size_t)256 * 4096 * 2);
  bf16_t* kpb  = (bf16_t*)alloc((size_t)4 * 4096 * 64 * 2);
  bf16_t* ctx  = (bf16_t*)alloc((size_t)4096 * 1024 * 2);
  // dead-after-gemm1 buffers; partial scratch overlays them (stream-ordered)
  size_t scratch_base = off;
  bf16_t* xb   = (bf16_t*)alloc((size_t)4096 * 1024 * 2);
  bf16_t* wqkv = (bf16_t*)alloc((size_t)1536 * 1024 * 2);
  float* Opart = (float*)(ws + scratch_base);            // 496*2*4096 f32
  float* lpart = Opart + (size_t)496 * 2 * 4096;         // 496*2*64 f32

  cvt_all<<<3328, 256, 0, stream>>>(x, wq, wk, wv, wo, xb, wqkv, wob);
  gemm_bt<bf16_t, 64, 64><<<dim3(24, 64), 256, 0, stream>>>(xb, wqkv, qkv,
                                                            4096, 1536, 1024,
                                                            kpb, vtb);
  attn_kernel<<<1024, 256, 0, stream>>>(qkv, kpb, vtb, ctx, Opart, lpart);
  norm_combine<<<496, 256, 0, stream>>>(Opart, lpart, ctx);
  gemm_bt<float, 64, 64><<<dim3(16, 64), 256, 0, stream>>>(ctx, wob, out,
                                                           4096, 1024, 1024,
                                                           nullptr, nullptr);
}

// Round 25
// 120.793 us; speedup vs baseline: 1.0528x; 1.0528x over previous
//
#include <hip/hip_runtime.h>

typedef __bf16 bf16_t;
typedef __bf16 bf16x8 __attribute__((ext_vector_type(8)));
typedef float  f32x4  __attribute__((ext_vector_type(4)));

#define MFMA16(a, b, c) __builtin_amdgcn_mfma_f32_16x16x32_bf16((a), (b), (c), 0, 0, 0)

__device__ __forceinline__ void gload_lds16(const void* g, void* l) {
  __builtin_amdgcn_global_load_lds((__attribute__((address_space(1))) void*)(g),
                                   (__attribute__((address_space(3))) void*)(l),
                                   16, 0, 0);
}

// ---------------------------------------------------------------- fused convert (x, wq, wk, wv, wo)
__global__ __launch_bounds__(256) void cvt_all(const float* __restrict__ x,
                                               const float* __restrict__ wq,
                                               const float* __restrict__ wk,
                                               const float* __restrict__ wv,
                                               const float* __restrict__ wo,
                                               bf16_t* __restrict__ xb,
                                               bf16_t* __restrict__ wqkv,
                                               bf16_t* __restrict__ wob) {
  int i = (blockIdx.x * 256 + threadIdx.x) * 8;
  const float* src;
  bf16_t* dst;
  int off;
  if (i < 4194304)      { src = x;  dst = xb;             off = i; }
  else if (i < 5242880) { src = wq; dst = wqkv;           off = i - 4194304; }
  else if (i < 5505024) { src = wk; dst = wqkv + 1048576; off = i - 5242880; }
  else if (i < 5767168) { src = wv; dst = wqkv + 1310720; off = i - 5505024; }
  else                  { src = wo; dst = wob;            off = i - 5767168; }
  const float4* pp = reinterpret_cast<const float4*>(src + off);
  float4 a = pp[0], b = pp[1];
  bf16x8 v;
  v[0] = (bf16_t)a.x; v[1] = (bf16_t)a.y; v[2] = (bf16_t)a.z; v[3] = (bf16_t)a.w;
  v[4] = (bf16_t)b.x; v[5] = (bf16_t)b.y; v[6] = (bf16_t)b.z; v[7] = (bf16_t)b.w;
  *reinterpret_cast<bf16x8*>(dst + off) = v;
}

// ---------------------------------------------------------------- GEMM  C[M,N] = A[M,K] * B[N,K]^T
// Template <T, BM, BN>: A-tile BM x 64, B-tile BN x 64; waves 2x2, each wave
// covers (BM/2) x (BN/2). Measured optimum (R22-R24 sweep): gemm1 BM=64/BN=128
// grid (12,64)=768 = 3/CU exact; gemm2 BM=64/BN=64 grid (16,64)=1024 = 4/CU
// exact. gemm1 at BN=64 regressed (dual-write + doubled L2 re-reads, R24).
// Dual-write epilogue when kp/vt non-null: cols [1024,1280) -> kp[4][4096][64]
// PRE-SCALED by 0.125*log2(e) (attn uses exp2 directly); cols [1280,1536) ->
// vt[256][4096] transposed.
template <typename T, int BM, int BN>
__global__ __launch_bounds__(256) void gemm_bt(const bf16_t* __restrict__ A,
                                               const bf16_t* __restrict__ B,
                                               T* __restrict__ C,
                                               int M, int N, int K,
                                               bf16_t* __restrict__ kp,
                                               bf16_t* __restrict__ vt) {
  constexpr int BK = 64;
  constexpr int MI = BM / 32;                    // row fragments per wave
  constexpr int NJ = BN / 32;                    // col fragments per wave
  int tid  = threadIdx.x;
  int lane = tid & 63, w = tid >> 6;
  int wr = w >> 1, wc = w & 1;
  int l15 = lane & 15, lhi = lane >> 4;
  int row0 = blockIdx.y * BM, col0 = blockIdx.x * BN;

  __shared__ alignas(16) char smem[(BM + BN) * 128];
  char* sA = smem;
  char* sB = smem + BM * 128;

  f32x4 acc[MI][NJ] = {};

  for (int k0 = 0; k0 < K; k0 += BK) {
#pragma unroll
    for (int i = 0; i < BM / 32; ++i) {          // A: BM*8 16B-chunks
      int c = i * 256 + tid;
      int r = c >> 3, kc = c & 7;
      int kk = k0 + ((kc ^ (r & 7)) << 3);
      gload_lds16(A + (size_t)(row0 + r) * K + kk, sA + c * 16);
    }
#pragma unroll
    for (int i = 0; i < BN / 32; ++i) {          // B: BN*8 16B-chunks
      int c = i * 256 + tid;
      int r = c >> 3, kc = c & 7;
      int kk = k0 + ((kc ^ (r & 7)) << 3);
      gload_lds16(B + (size_t)(col0 + r) * K + kk, sB + c * 16);
    }
    __syncthreads();
#pragma unroll
    for (int s = 0; s < 2; ++s) {
      bf16x8 af[MI], bfr[NJ];
#pragma unroll
      for (int mi = 0; mi < MI; ++mi) {
        int r = wr * (BM / 2) + mi * 16 + l15;
        af[mi] = *reinterpret_cast<const bf16x8*>(
            sA + r * 128 + (((s * 4 + lhi) ^ (r & 7)) << 4));
      }
#pragma unroll
      for (int nj = 0; nj < NJ; ++nj) {
        int r = wc * (BN / 2) + nj * 16 + l15;
        bfr[nj] = *reinterpret_cast<const bf16x8*>(
            sB + r * 128 + (((s * 4 + lhi) ^ (r & 7)) << 4));
      }
#pragma unroll
      for (int mi = 0; mi < MI; ++mi)
#pragma unroll
        for (int nj = 0; nj < NJ; ++nj)
          acc[mi][nj] = MFMA16(af[mi], bfr[nj], acc[mi][nj]);
    }
    __syncthreads();
  }

  const float KSCALE = 0.18033688f;   // 0.125 * log2(e)
#pragma unroll
  for (int mi = 0; mi < MI; ++mi)
#pragma unroll
    for (int nj = 0; nj < NJ; ++nj) {
      int colb = col0 + wc * (BN / 2) + nj * 16 + l15;
      int rowb = row0 + wr * (BM / 2) + mi * 16 + lhi * 4;
      if (kp != nullptr && colb >= 1024) {
        if (colb < 1280) {
          int gg = (colb - 1024) >> 6, d = (colb - 1024) & 63;
          bf16_t* kdst = kp + ((size_t)gg * 4096 + rowb) * 64 + d;
#pragma unroll
          for (int r2 = 0; r2 < 4; ++r2)
            kdst[r2 * 64] = (bf16_t)(acc[mi][nj][r2] * KSCALE);
        } else {
          union { bf16_t hh[4]; uint64_t u; } a;
#pragma unroll
          for (int r2 = 0; r2 < 4; ++r2) a.hh[r2] = (bf16_t)acc[mi][nj][r2];
          *reinterpret_cast<uint64_t*>(vt + (size_t)(colb - 1280) * 4096 + rowb) = a.u;
        }
      } else {
#pragma unroll
        for (int r2 = 0; r2 < 4; ++r2)
          C[(size_t)(rowb + r2) * N + colb] = (T)acc[mi][nj][r2];
      }
    }
}

// ---------------------------------------------------------------- flash attention (causal GQA)
// R21 config (best measured: attn 74.3us): BK=64, 4 waves x 16 q-rows, shared
// double-buffered K+V staging via global_load_lds (pre-swizzled source), P via
// wave-private XOR-swizzled LDS, pair-and-split balance (1024 uniform blocks),
// partials straight to scratch, norm_combine. l accumulated on the matrix
// pipe: lacc = mfma(ap, ones, lacc); lacc[r] lane-aligned with O rows.
// K pre-scaled by 0.125*log2(e) -> P = exp2(st) directly.
__global__ __launch_bounds__(256, 2) void attn_kernel(const bf16_t* __restrict__ qkv,
                                                      const bf16_t* __restrict__ kp,
                                                      const bf16_t* __restrict__ vt,
                                                      bf16_t* __restrict__ ctx,
                                                      float* __restrict__ Opart,
                                                      float* __restrict__ lpart) {
  int tid = threadIdx.x, lane = tid & 63, w = tid >> 6;
  int l15 = lane & 15, lhi = lane >> 4;
  int e = l15 & 7;
  int bid = blockIdx.x;
  int pos = bid & 15, qq = bid >> 4;             // qq 0..63
  int p = qq >> 1, half = qq & 1;
  int g = (pos & 7) >> 1;                        // KV group -> XCDs {2g, 2g+1}
  int h = g * 4 + (((pos >> 3) << 1) | (pos & 1));

  __shared__ alignas(16) char kv[2][16384];      // [buf][K 8KB | V 8KB], swizzled
  __shared__ alignas(16) char pb_all[4][2048];   // per-wave P [16 rows][128B], XOR chunks
  char* pbuf = pb_all[w];

  const bf16_t* kbase = kp + (size_t)g * 4096 * 64;
  const bf16_t* vbase = vt + (size_t)g * 64 * 4096;

  auto STAGE = [&](int j0, int b) {
#pragma unroll
    for (int i = 0; i < 2; ++i) {
      int c = i * 256 + tid;                     // 512 chunks of 16B
      int r = c >> 3, kc = c & 7;
      int d8 = kc ^ (r & 7);
      gload_lds16(kbase + (size_t)(j0 + r) * 64 + d8 * 8, &kv[b][c * 16]);
    }
#pragma unroll
    for (int i = 0; i < 2; ++i) {
      int c = i * 256 + tid;
      int r = c >> 3, kc = c & 7;
      int d8 = kc ^ (r & 7);
      gload_lds16(vbase + (size_t)r * 4096 + j0 + d8 * 8, &kv[b][8192 + c * 16]);
    }
  };

  bf16x8 ones;
#pragma unroll
  for (int ii = 0; ii < 8; ++ii) ones[ii] = (bf16_t)1.0f;

  auto runPhase = [&](int tile, int sbeg, int send, bool fin,
                      float* Oslot, float* lslot) {
    int r0 = tile * 64;
    int wr0 = r0 + w * 16;                       // this wave's 16 q-rows

    bf16x8 qf[2];
#pragma unroll
    for (int ks = 0; ks < 2; ++ks)
      qf[ks] = *reinterpret_cast<const bf16x8*>(
          qkv + (size_t)(wr0 + l15) * 1536 + h * 64 + ks * 32 + lhi * 8);

    f32x4 O[4] = {};
    f32x4 lacc = {0.f, 0.f, 0.f, 0.f};

    STAGE(sbeg * 64, 0);
    __syncthreads();

    for (int step = sbeg; step < send; ++step) {
      int b = (step - sbeg) & 1;
      if (step + 1 < send) STAGE((step + 1) * 64, b ^ 1);
      int j0 = step * 64;
      const char* kt  = kv[b];
      const char* vtl = kv[b] + 8192;
      bool diag = (j0 + 64 > r0);
#pragma unroll
      for (int nj = 0; nj < 4; ++nj) {
        int kr = nj * 16 + l15;                  // key row in tile
        const char* krow = kt + kr * 128;
        bf16x8 k0 = *reinterpret_cast<const bf16x8*>(krow + ((lhi ^ (kr & 7)) << 4));
        bf16x8 k1 = *reinterpret_cast<const bf16x8*>(krow + (((4 + lhi) ^ (kr & 7)) << 4));
        f32x4 t = {0.f, 0.f, 0.f, 0.f};
        t = MFMA16(k0, qf[0], t);
        t = MFMA16(k1, qf[1], t);
        if (diag) {
          int qr = wr0 + l15;
#pragma unroll
          for (int r = 0; r < 4; ++r) {
            int key = j0 + nj * 16 + lhi * 4 + r;
            if (key > qr) t[r] = -1e30f;
          }
        }
        int sw = (nj * 2 + (lhi >> 1)) ^ e;      // XOR chunk swizzle (wave-private)
        union { bf16_t hh[4]; uint64_t u; } a;
#pragma unroll
        for (int r = 0; r < 4; ++r) a.hh[r] = (bf16_t)exp2f(t[r]);
        *reinterpret_cast<uint64_t*>(pbuf + l15 * 128 + sw * 16 + ((lhi & 1) << 3)) = a.u;
      }
      // ---- PV: A = P (row = l15), B = V^T (hd = l15); l += P . ones (MFMA)
      bf16x8 ap[2];
#pragma unroll
      for (int ks = 0; ks < 2; ++ks)
        ap[ks] = *reinterpret_cast<const bf16x8*>(
            pbuf + l15 * 128 + (((ks * 4 + lhi) ^ e) << 4));
      lacc = MFMA16(ap[0], ones, lacc);
      lacc = MFMA16(ap[1], ones, lacc);
#pragma unroll
      for (int h4 = 0; h4 < 4; ++h4) {
        int vr = h4 * 16 + l15;                  // hd row in tile
        const char* vrow = vtl + vr * 128;
        bf16x8 v0 = *reinterpret_cast<const bf16x8*>(vrow + ((lhi ^ (vr & 7)) << 4));
        bf16x8 v1 = *reinterpret_cast<const bf16x8*>(vrow + (((4 + lhi) ^ (vr & 7)) << 4));
        O[h4] = MFMA16(ap[0], v0, O[h4]);
        O[h4] = MFMA16(ap[1], v1, O[h4]);
      }
      __syncthreads();   // drains staging vmcnt; protects both buffers
    }

    // ---- epilogue: lacc[r] = l for row wr0+lhi*4+r (lane-aligned with O)
    if (fin) {
#pragma unroll
      for (int h4 = 0; h4 < 4; ++h4)
#pragma unroll
        for (int r = 0; r < 4; ++r) {
          int row = wr0 + lhi * 4 + r;
          ctx[(size_t)row * 1024 + h * 64 + h4 * 16 + l15] =
              (bf16_t)(O[h4][r] / lacc[r]);
        }
    } else {
      if (l15 == 0) {
#pragma unroll
        for (int r = 0; r < 4; ++r) lslot[w * 16 + lhi * 4 + r] = lacc[r];
      }
#pragma unroll
      for (int h4 = 0; h4 < 4; ++h4)
#pragma unroll
        for (int r = 0; r < 4; ++r)
          Oslot[(size_t)(w * 16 + lhi * 4 + r) * 64 + h4 * 16 + l15] = O[h4][r];
    }
  };

  if (half == 0) {
    bool fin = (p == 31);   // tile 32 has exactly 33 steps -> complete
    if (fin) {
      runPhase(63 - p, 0, 33, true, nullptr, nullptr);
    } else {
      int u = (30 - p) * 16 + h;
      runPhase(63 - p, 0, 33, false,
               Opart + ((size_t)u * 2 + 0) * 4096, lpart + ((size_t)u * 2 + 0) * 64);
    }
  } else {
    if (p < 31) {
      int u = (30 - p) * 16 + h;
      runPhase(63 - p, 33, 64 - p, false,
               Opart + ((size_t)u * 2 + 1) * 4096, lpart + ((size_t)u * 2 + 1) * 64);
    }
    runPhase(p, 0, p + 1, true, nullptr, nullptr);
  }
}

// ---------------------------------------------------------------- combine split-tile partials
__global__ __launch_bounds__(256) void norm_combine(const float* __restrict__ Opart,
                                                    const float* __restrict__ lpart,
                                                    bf16_t* __restrict__ ctx) {
  int u = blockIdx.x;
  int T = 33 + (u >> 4), h = u & 15;
  int t = threadIdx.x;
  int row = t >> 2, q = t & 3;                   // 64 rows x 4 quarters
  const float* O0 = Opart + (size_t)u * 2 * 4096;
  const float* O1 = O0 + 4096;
  const float* l0 = lpart + (size_t)u * 2 * 64;
  const float* l1 = l0 + 64;
  float il = 1.0f / (l0[row] + l1[row]);
#pragma unroll
  for (int i = 0; i < 4; ++i) {
    int idx = row * 64 + q * 16 + i * 4;
    f32x4 a = *reinterpret_cast<const f32x4*>(O0 + idx);
    f32x4 b = *reinterpret_cast<const f32x4*>(O1 + idx);
    union { bf16_t hh[4]; uint64_t uu; } o;
#pragma unroll
    for (int r = 0; r < 4; ++r) o.hh[r] = (bf16_t)((a[r] + b[r]) * il);
    *reinterpret_cast<uint64_t*>(
        ctx + (size_t)(T * 64 + row) * 1024 + h * 64 + q * 16 + i * 4) = o.uu;
  }
}

// ---------------------------------------------------------------- launch
extern "C" void kernel_launch(void* const* d_in, const int* in_sizes, int n_in,
                              void* d_out, int out_size, void* d_ws, size_t ws_size,
                              hipStream_t stream) {
  const float* x  = (const float*)d_in[0];
  const float* wq = (const float*)d_in[1];
  const float* wk = (const float*)d_in[2];
  const float* wv = (const float*)d_in[3];
  const float* wo = (const float*)d_in[4];
  float* out = (float*)d_out;

  char* ws = (char*)d_ws;
  size_t off = 0;
  auto alloc = [&](size_t b) {
    char* p = ws + off;
    off += (b + 255) & ~(size_t)255;
    return p;
  };
  // live-through-attn buffers first
  bf16_t* wob  = (bf16_t*)alloc((size_t)1024 * 1024 * 2);
  bf16_t* qkv  = (bf16_t*)alloc((size_t)4096 * 1536 * 2);
  bf16_t* vtb  = (bf16_t*)alloc((size_t)256 * 4096 * 2);
  bf16_t* kpb  = (bf16_t*)alloc((size_t)4 * 4096 * 64 * 2);
  bf16_t* ctx  = (bf16_t*)alloc((size_t)4096 * 1024 * 2);
  // dead-after-gemm1 buffers; partial scratch overlays them (stream-ordered)
  size_t scratch_base = off;
  bf16_t* xb   = (bf16_t*)alloc((size_t)4096 * 1024 * 2);
  bf16_t* wqkv = (bf16_t*)alloc((size_t)1536 * 1024 * 2);
  float* Opart = (float*)(ws + scratch_base);            // 496*2*4096 f32
  float* lpart = Opart + (size_t)496 * 2 * 4096;         // 496*2*64 f32

  cvt_all<<<3328, 256, 0, stream>>>(x, wq, wk, wv, wo, xb, wqkv, wob);
  gemm_bt<bf16_t, 64, 128><<<dim3(12, 64), 256, 0, stream>>>(xb, wqkv, qkv,
                                                             4096, 1536, 1024,
                                                             kpb, vtb);
  attn_kernel<<<1024, 256, 0, stream>>>(qkv, kpb, vtb, ctx, Opart, lpart);
  norm_combine<<<496, 256, 0, stream>>>(Opart, lpart, ctx);
  gemm_bt<float, 64, 64><<<dim3(16, 64), 256, 0, stream>>>(ctx, wob, out,
                                                           4096, 1024, 1024,
                                                           nullptr, nullptr);
}